// Round 5
// baseline (37.222 us; speedup 1.0000x reference)
//
#include <hip/hip_runtime.h>
#include <math.h>
#include <stdint.h>

#define NB 16
#define NH 512
#define NW 512
#define PLANE (NH * NW)
#define INF_D 1.0e9f
#define INF2 1.0e18f   // == fl(1e9f*1e9f), matches reference d*d rounding
#define BIG 3.0e38f
#define NSEG 64        // 512 / 8
#define HROW 516       // LDS row stride in floats for [col][k] layout

// ---------------------------------------------------------------------------
// K1: exact 1-D nearest-zero distance along axis 0 (B) -> u8 code.
// code = d (0..15 finite, 31 = INF) | (isnan(x) << 7). Bit-exact: finite d is
// an exact small integer; squaring is deferred (exactly) to K2's decode.
// ---------------------------------------------------------------------------
__global__ __launch_bounds__(256) void k_pass_b(const float* __restrict__ x,
                                                unsigned char* __restrict__ code) {
    int idx4 = (blockIdx.x * 256 + threadIdx.x) * 4;
    if (idx4 >= PLANE) return;
    float4 d0[NB], d[NB];
    int nm[NB];
#pragma unroll
    for (int b = 0; b < NB; ++b) {
        float4 v = *reinterpret_cast<const float4*>(&x[(size_t)b * PLANE + idx4]);
        nm[b] = (isnan(v.x) ? 1 : 0) | (isnan(v.y) ? 2 : 0) |
                (isnan(v.z) ? 4 : 0) | (isnan(v.w) ? 8 : 0);
        d0[b].x = (v.x == 0.0f) ? 0.0f : INF_D;
        d0[b].y = (v.y == 0.0f) ? 0.0f : INF_D;
        d0[b].z = (v.z == 0.0f) ? 0.0f : INF_D;
        d0[b].w = (v.w == 0.0f) ? 0.0f : INF_D;
    }
#pragma unroll
    for (int c = 0; c < 4; ++c) {
        float cc = INF_D;
#pragma unroll
        for (int b = 0; b < NB; ++b) {
            cc = fminf(cc + 1.0f, ((float*)&d0[b])[c]);
            ((float*)&d[b])[c] = cc;
        }
        cc = INF_D;
#pragma unroll
        for (int b = NB - 1; b >= 0; --b) {
            cc = fminf(cc + 1.0f, ((float*)&d0[b])[c]);
            ((float*)&d[b])[c] = fminf(((float*)&d[b])[c], cc);
        }
    }
#pragma unroll
    for (int b = 0; b < NB; ++b) {
        uchar4 o;
        float* p = (float*)&d[b];
        int di0 = (p[0] >= 1.0e8f) ? 31 : (int)p[0];
        int di1 = (p[1] >= 1.0e8f) ? 31 : (int)p[1];
        int di2 = (p[2] >= 1.0e8f) ? 31 : (int)p[2];
        int di3 = (p[3] >= 1.0e8f) ? 31 : (int)p[3];
        o.x = (unsigned char)(di0 | ((nm[b] & 1) << 7));
        o.y = (unsigned char)(di1 | ((nm[b] & 2) << 6));
        o.z = (unsigned char)(di2 | ((nm[b] & 4) << 5));
        o.w = (unsigned char)(di3 | ((nm[b] & 8) << 4));
        *reinterpret_cast<uchar4*>(&code[(size_t)b * PLANE + idx4]) = o;
    }
}

// ---------------------------------------------------------------------------
// Shared eval: seg=8 ring-pruned min-plus over one LDS row (h = g + k^2,
// [col][k] layout, stride HROW). best[j] accumulates min_k(h[k] - 2*i_j*k).
// True-space prune: bmax = max_j(i_j^2 + best[j]); seg s at ring r skippable
// when gap^2 + min_seg(g) >= bmax, gap = 8(r-1)+1; break when gap^2 >= bmax.
// min3/max3 patterns: fminf(fminf(a,b),c) -> v_min3_f32.
// ---------------------------------------------------------------------------
__device__ __forceinline__ void eval_minplus(const float* __restrict__ hrow,
                                             const float* __restrict__ sminw,
                                             int q, float* best,
                                             const float* neg2i,
                                             const float* ifl) {
    float bmax = BIG;
    for (int step = 0; step < 2 * NSEG - 1; ++step) {
        int r = (step + 1) >> 1;
        float gapf = (float)(8 * (r - 1) + 1);
        float gap2 = gapf * gapf;
        if ((step & 1) && gap2 >= bmax) break;
        int s = (step & 1) ? (q - r) : (q + r);
        if (s < 0 || s >= NSEG) continue;
        if (step && (gap2 + sminw[s * 16] >= bmax)) continue;
        const float* hp = hrow + s * 8;
        float4 A = *reinterpret_cast<const float4*>(hp);
        float4 B = *reinterpret_cast<const float4*>(hp + 4);
        float s8f = (float)(s * 8);
#pragma unroll
        for (int j = 0; j < 8; ++j) {
            float n2 = neg2i[j];
            float c0 = fmaf(n2, s8f, A.x);
            float c1 = fmaf(n2, s8f + 1.0f, A.y);
            float c2 = fmaf(n2, s8f + 2.0f, A.z);
            float c3 = fmaf(n2, s8f + 3.0f, A.w);
            float c4 = fmaf(n2, s8f + 4.0f, B.x);
            float c5 = fmaf(n2, s8f + 5.0f, B.y);
            float c6 = fmaf(n2, s8f + 6.0f, B.z);
            float c7 = fmaf(n2, s8f + 7.0f, B.w);
            float bb = fminf(fminf(best[j], c0), c1);
            bb = fminf(fminf(bb, c2), c3);
            bb = fminf(fminf(bb, c4), c5);
            bb = fminf(fminf(bb, c6), c7);
            best[j] = bb;
        }
        float t0 = fmaf(ifl[0], ifl[0], best[0]);
        float t1 = fmaf(ifl[1], ifl[1], best[1]);
        float t2 = fmaf(ifl[2], ifl[2], best[2]);
        float t3 = fmaf(ifl[3], ifl[3], best[3]);
        float t4 = fmaf(ifl[4], ifl[4], best[4]);
        float t5 = fmaf(ifl[5], ifl[5], best[5]);
        float t6 = fmaf(ifl[6], ifl[6], best[6]);
        float t7 = fmaf(ifl[7], ifl[7], best[7]);
        float m = fmaxf(fmaxf(t0, t1), t2);
        m = fmaxf(fmaxf(m, t3), t4);
        m = fmaxf(fmaxf(m, t5), t6);
        bmax = fmaxf(m, t7);
    }
}

// ---------------------------------------------------------------------------
// K2: min-plus along H. Block = 1024 thr: one b, 16-wide w tile, all 512 i.
// Stages u8 codes -> hs[w][k] = d^2 + k^2 (exact int), flags in LDS.
// Writes fl(fl(i^2+best) + wg^2) with NaN flag in the sign bit.
// ---------------------------------------------------------------------------
__global__ __launch_bounds__(1024) void k_pass_h(const unsigned char* __restrict__ code,
                                                 float* __restrict__ out) {
    __shared__ float hs[16 * HROW];
    __shared__ float smin[NSEG * 16];
    __shared__ unsigned char flg[NH * 16];
    int b = blockIdx.y;
    int w0 = blockIdx.x * 16;
    const unsigned char* gb8 = code + (size_t)b * PLANE + w0;
    int t = threadIdx.x;

    for (int m = t; m < 2048; m += 1024) {
        int k = m >> 2;
        int bo = (m & 3) * 4;
        unsigned int u = *reinterpret_cast<const unsigned int*>(gb8 + (size_t)k * NW + bo);
        int kk = k * k;
#pragma unroll
        for (int e = 0; e < 4; ++e) {
            int c = (u >> (8 * e)) & 0xFF;
            int dl = c & 31;
            float g = (dl == 31) ? INF2 : (float)(dl * dl + kk);  // exact int
            hs[(bo + e) * HROW + k] = g;
            flg[k * 16 + (bo + e)] = (unsigned char)(c >> 7);
        }
    }
    __syncthreads();
    {
        int s = t >> 4, w = t & 15;
        const float* hp = &hs[w * HROW + s * 8];
        float4 A = *reinterpret_cast<const float4*>(hp);
        float4 B = *reinterpret_cast<const float4*>(hp + 4);
        int k0 = s * 8;
        float m0 = fminf(fminf(A.x - (float)(k0 * k0), A.y - (float)((k0 + 1) * (k0 + 1))),
                         A.z - (float)((k0 + 2) * (k0 + 2)));
        float m1 = fminf(fminf(A.w - (float)((k0 + 3) * (k0 + 3)), B.x - (float)((k0 + 4) * (k0 + 4))),
                         B.y - (float)((k0 + 5) * (k0 + 5)));
        float m2 = fminf(B.z - (float)((k0 + 6) * (k0 + 6)), B.w - (float)((k0 + 7) * (k0 + 7)));
        smin[t] = fminf(fminf(m0, m1), m2);
    }
    __syncthreads();

    int w = t & 15, q = t >> 4;
    int i0 = q * 8;
    float best[8], neg2i[8], ifl[8];
#pragma unroll
    for (int j = 0; j < 8; ++j) {
        best[j] = BIG;
        ifl[j] = (float)(i0 + j);
        neg2i[j] = (float)(-2 * (i0 + j));
    }
    eval_minplus(&hs[w * HROW], &smin[w], q, best, neg2i, ifl);

    float wgf = (float)(w0 + w);
    float* ob = out + (size_t)b * PLANE + w0 + w;
#pragma unroll
    for (int j = 0; j < 8; ++j) {
        float v = fmaf(ifl[j], ifl[j], best[j]);   // exact d^2 after B+H
        float v2 = fmaf(wgf, wgf, v);              // fold K3's +k^2 (exact)
        unsigned int bits = __float_as_uint(v2) |
                            ((unsigned int)flg[(i0 + j) * 16 + w] << 31);
        ob[(size_t)(i0 + j) * NW] = __uint_as_float(bits);
    }
}

// ---------------------------------------------------------------------------
// K3: min-plus along W (contiguous lines), in-place on out. +k^2 pre-folded
// by K2; NaN flag in sign bit -> strip at staging. sqrt + NaN epilogue.
// ---------------------------------------------------------------------------
__global__ __launch_bounds__(1024) void k_pass_w(float* __restrict__ out) {
    __shared__ float hs[16 * HROW];
    __shared__ float smin[NSEG * 16];
    __shared__ unsigned char flg[16 * NW];
    int line0 = blockIdx.x * 16;
    float* gb = out + (size_t)line0 * NW;
    int t = threadIdx.x;

    for (int m = t; m < 2048; m += 1024) {
        float4 v = *reinterpret_cast<const float4*>(gb + (size_t)m * 4);
        int line = m >> 7;
        int k = (m * 4) & 511;
        float4 o;
        unsigned int u0 = __float_as_uint(v.x), u1 = __float_as_uint(v.y);
        unsigned int u2 = __float_as_uint(v.z), u3 = __float_as_uint(v.w);
        flg[line * NW + k] = (unsigned char)(u0 >> 31);
        flg[line * NW + k + 1] = (unsigned char)(u1 >> 31);
        flg[line * NW + k + 2] = (unsigned char)(u2 >> 31);
        flg[line * NW + k + 3] = (unsigned char)(u3 >> 31);
        o.x = __uint_as_float(u0 & 0x7fffffffu);
        o.y = __uint_as_float(u1 & 0x7fffffffu);
        o.z = __uint_as_float(u2 & 0x7fffffffu);
        o.w = __uint_as_float(u3 & 0x7fffffffu);
        *reinterpret_cast<float4*>(&hs[line * HROW + k]) = o;
    }
    __syncthreads();
    {
        int s = t >> 4, line = t & 15;
        const float* hp = &hs[line * HROW + s * 8];
        float4 A = *reinterpret_cast<const float4*>(hp);
        float4 B = *reinterpret_cast<const float4*>(hp + 4);
        int k0 = s * 8;
        float m0 = fminf(fminf(A.x - (float)(k0 * k0), A.y - (float)((k0 + 1) * (k0 + 1))),
                         A.z - (float)((k0 + 2) * (k0 + 2)));
        float m1 = fminf(fminf(A.w - (float)((k0 + 3) * (k0 + 3)), B.x - (float)((k0 + 4) * (k0 + 4))),
                         B.y - (float)((k0 + 5) * (k0 + 5)));
        float m2 = fminf(B.z - (float)((k0 + 6) * (k0 + 6)), B.w - (float)((k0 + 7) * (k0 + 7)));
        smin[t] = fminf(fminf(m0, m1), m2);
    }
    __syncthreads();

    int line = t & 15, q = t >> 4;
    int i0 = q * 8;
    float best[8], neg2i[8], ifl[8];
#pragma unroll
    for (int j = 0; j < 8; ++j) {
        best[j] = BIG;
        ifl[j] = (float)(i0 + j);
        neg2i[j] = (float)(-2 * (i0 + j));
    }
    eval_minplus(&hs[line * HROW], &smin[line], q, best, neg2i, ifl);

    float v[8];
#pragma unroll
    for (int j = 0; j < 8; ++j) {
        float m = fmaf(ifl[j], ifl[j], best[j]);  // exact final d^2
        float sq = sqrtf(m);
        v[j] = flg[line * NW + i0 + j] ? __builtin_nanf("") : sq;
    }
    float* op = gb + (size_t)line * NW + i0;
    float4 oa, ob4;
    oa.x = v[0]; oa.y = v[1]; oa.z = v[2]; oa.w = v[3];
    ob4.x = v[4]; ob4.y = v[5]; ob4.z = v[6]; ob4.w = v[7];
    *reinterpret_cast<float4*>(op) = oa;
    *reinterpret_cast<float4*>(op + 4) = ob4;
}

extern "C" void kernel_launch(void* const* d_in, const int* in_sizes, int n_in,
                              void* d_out, int out_size, void* d_ws, size_t ws_size,
                              hipStream_t stream) {
    (void)in_sizes; (void)n_in; (void)out_size; (void)ws_size;
    const float* x = (const float*)d_in[0];
    float* out = (float*)d_out;
    unsigned char* code = (unsigned char*)d_ws;  // 4.2 MB u8 codes

    // K1: x -> u8 codes (d along B + NaN flag)
    k_pass_b<<<dim3(PLANE / 4 / 256), 256, 0, stream>>>(x, code);
    // K2: min-plus along H: codes -> out (f32, +w^2 folded, NaN in sign)
    k_pass_h<<<dim3(NW / 16, NB), 1024, 0, stream>>>(code, out);
    // K3: min-plus along W, in-place on out, sqrt + NaN mask
    k_pass_w<<<dim3(NB * NH / 16), 1024, 0, stream>>>(out);
}